// Round 8
// baseline (2484.520 us; speedup 1.0000x reference)
//
#include <hip/hip_runtime.h>
#include <hip/hip_bf16.h>
#include <stdint.h>

#define NN 100000
#define NE 1600000
#define NBK 1563      // ceil(NN/64) dst-buckets
#define BCAP 1536     // slots per bucket (lambda=1024, +16 sigma)

typedef __attribute__((ext_vector_type(4))) float f32x4;
typedef __attribute__((ext_vector_type(2))) float f32x2;
typedef __attribute__((ext_vector_type(8))) __bf16 bf16x8;
typedef __attribute__((ext_vector_type(8))) short s16x8;
typedef __attribute__((ext_vector_type(4))) unsigned int u32x4;

__device__ __forceinline__ unsigned short f2bf(float f) {
  unsigned int u = __builtin_bit_cast(unsigned int, f);
  u += 0x7fffu + ((u >> 16) & 1u);
  return (unsigned short)(u >> 16);
}

__device__ __forceinline__ f32x4 mfma16(bf16x8 a, bf16x8 b, f32x4 c) {
  return __builtin_amdgcn_mfma_f32_16x16x32_bf16(a, b, c, 0, 0, 0);
}

// ---------------------------------------------------------------------------
// setup: node_state -> bf16 table; msg weights + global -> bf16
// ---------------------------------------------------------------------------
__global__ void convert_kernel(const float* __restrict__ ns,
                               const float* __restrict__ w1, const float* __restrict__ w2,
                               const float* __restrict__ g,
                               unsigned short* __restrict__ node_bf,
                               unsigned short* __restrict__ w1b, unsigned short* __restrict__ w2b,
                               unsigned short* __restrict__ gb)
{
  const int tid = blockIdx.x * 256 + threadIdx.x;
  const int stride = gridDim.x * 256;
  for (int i = tid; i < NN * 128; i += stride) node_bf[i] = f2bf(ns[i]);
  if (tid < 256 * 128) w1b[tid] = f2bf(w1[tid]);
  if (tid < 128 * 128) w2b[tid] = f2bf(w2[tid]);
  if (tid < 64) gb[tid] = f2bf(g[tid]);
}

// ---------------------------------------------------------------------------
// edge msg kernel (original edge order -> sequential edge_state stream):
// msg = MLP(concat(node_bf[src], edge_state, gs)) via bf16 MFMA;
// row appended as fp8 (128 B) to its dst-bucket stream (cursor atomicAdd).
// Bucketed append => ~1563 hot L2 write streams => full-line combining.
// ---------------------------------------------------------------------------
__global__ __launch_bounds__(256, 3) void edge_msg_kernel(
    const int* __restrict__ ei,
    const float* __restrict__ edge_state,
    const unsigned short* __restrict__ node_bf,
    const unsigned short* __restrict__ w1b,
    const unsigned short* __restrict__ w2b,
    const float* __restrict__ bias1g,
    const float* __restrict__ bias2g,
    const unsigned short* __restrict__ gb,
    int* __restrict__ bcur,
    unsigned int* __restrict__ msgs,          // [NBK*BCAP][32] u32 (128 fp8/row)
    unsigned char* __restrict__ dst8)         // [NBK*BCAP] dst & 63
{
  __shared__ unsigned short sX[64 * 256];  // 32 KB staging; front 16 KB reused for msg tile
  __shared__ unsigned short sH[64 * 128];  // 16 KB h1
  __shared__ int sDst[64];

  const int t = threadIdx.x;
  const int lane = t & 63;
  const int wv = t >> 6;
  const int l15 = lane & 15;
  const int lq = lane >> 4;

  // preload W1/W2 B-fragments (per-wave column slice)
  bf16x8 b1f[8][2], b2f[4][2];
  float bs1[2], bs2[2];
  for (int n = 0; n < 2; ++n) {
    const int col = wv * 32 + n * 16 + l15;
    bs1[n] = bias1g[col];
    bs2[n] = bias2g[col];
    for (int ks = 0; ks < 8; ++ks) {
      const int k0 = ks * 32 + lq * 8;
      s16x8 v;
#pragma unroll
      for (int j = 0; j < 8; ++j) v[j] = (short)w1b[(k0 + j) * 128 + col];
      b1f[ks][n] = __builtin_bit_cast(bf16x8, v);
    }
    for (int ks = 0; ks < 4; ++ks) {
      const int k0 = ks * 32 + lq * 8;
      s16x8 v;
#pragma unroll
      for (int j = 0; j < 8; ++j) v[j] = (short)w2b[(k0 + j) * 128 + col];
      b2f[ks][n] = __builtin_bit_cast(bf16x8, v);
    }
  }

  const int r = t >> 2;   // edge row within tile
  const int p = t & 3;    // quarter of the row
  const int rs = r & 7;   // swizzle key

  u32x4 gR0, gR1;
  {
    const u32x4* g = (const u32x4*)(gb + p * 16);
    gR0 = g[0]; gR1 = g[1];
  }

  const int grid = gridDim.x;
  const int NT = NE / 64;

  // ---- prologue: gather tile0; indices for tile1 ----
  u32x4 pfN[4];
  f32x4 pfE[4];
  int srcNext, dstNext, dstCur;
  {
    const int e0 = blockIdx.x * 64 + r;
    const int s0 = ei[e0];
    dstCur = ei[NE + e0];
    const u32x4* nb = (const u32x4*)(node_bf + (size_t)s0 * 128);
    const f32x4* es = (const f32x4*)(edge_state + (size_t)e0 * 64);
#pragma unroll
    for (int j = 0; j < 4; ++j) { pfN[j] = nb[p * 4 + j]; pfE[j] = es[p * 4 + j]; }
    const int e1 = min((blockIdx.x + grid) * 64 + r, NE - 1);
    srcNext = ei[e1];
    dstNext = ei[NE + e1];
  }

  for (int tile = blockIdx.x; tile < NT; tile += grid) {
    __syncthreads();  // prior iteration's out-store done reading sX front

    // ---- stage: reg -> LDS ----
    if (p == 0) sDst[r] = dstCur;
#pragma unroll
    for (int j = 0; j < 4; ++j) {   // node chunks 0..15 (bf16)
      const int c = p * 4 + j;
      *(u32x4*)((char*)sX + r * 512 + ((c ^ rs) * 16)) = pfN[j];
    }
    {  // edge chunks 16..23 (f32 -> bf16)
      unsigned short bufa[8], bufb[8];
#pragma unroll
      for (int i = 0; i < 4; ++i) {
        bufa[i] = f2bf(pfE[0][i]); bufa[4 + i] = f2bf(pfE[1][i]);
        bufb[i] = f2bf(pfE[2][i]); bufb[4 + i] = f2bf(pfE[3][i]);
      }
      const int c = 16 + 2 * p;
      *(u32x4*)((char*)sX + r * 512 + ((c ^ rs) * 16)) = *(u32x4*)bufa;
      *(u32x4*)((char*)sX + r * 512 + (((c + 1) ^ rs) * 16)) = *(u32x4*)bufb;
    }
    {  // global chunks 24..31
      const int c = 24 + 2 * p;
      *(u32x4*)((char*)sX + r * 512 + ((c ^ rs) * 16)) = gR0;
      *(u32x4*)((char*)sX + r * 512 + (((c + 1) ^ rs) * 16)) = gR1;
    }
    __syncthreads();

    // ---- issue next tile's gathers (latency hidden by MFMA) ----
    {
      const int tn = tile + grid;
      const int eN = min(tn * 64 + r, NE - 1);
      const u32x4* nb = (const u32x4*)(node_bf + (size_t)srcNext * 128);
      const f32x4* es = (const f32x4*)(edge_state + (size_t)eN * 64);
#pragma unroll
      for (int j = 0; j < 4; ++j) { pfN[j] = nb[p * 4 + j]; pfE[j] = es[p * 4 + j]; }
      dstCur = dstNext;
      const int e2 = min((tn + grid) * 64 + r, NE - 1);
      srcNext = ei[e2];
      dstNext = ei[NE + e2];
    }

    // ---- phase 1: h1 = relu(X @ W1 + b1) ----
    f32x4 acc[4][2];
#pragma unroll
    for (int m = 0; m < 4; ++m)
#pragma unroll
      for (int n = 0; n < 2; ++n)
        acc[m][n] = (f32x4){bs1[n], bs1[n], bs1[n], bs1[n]};
#pragma unroll
    for (int ks = 0; ks < 8; ++ks) {
      bf16x8 a[4];
#pragma unroll
      for (int m = 0; m < 4; ++m) {
        const int row = m * 16 + l15;
        a[m] = *(const bf16x8*)((const char*)sX + row * 512 + (((4 * ks + lq) ^ (row & 7)) * 16));
      }
#pragma unroll
      for (int m = 0; m < 4; ++m)
#pragma unroll
        for (int n = 0; n < 2; ++n)
          acc[m][n] = mfma16(a[m], b1f[ks][n], acc[m][n]);
    }
#pragma unroll
    for (int m = 0; m < 4; ++m)
#pragma unroll
      for (int n = 0; n < 2; ++n)
#pragma unroll
        for (int i = 0; i < 4; ++i) {
          const int row = m * 16 + lq * 4 + i;
          const int col = wv * 32 + n * 16 + l15;
          float v = acc[m][n][i];
          v = v > 0.f ? v : 0.f;
          *(unsigned short*)((char*)sH + row * 256 +
                             ((((col >> 3) ^ (row & 7)) * 16) + (col & 7) * 2)) = f2bf(v);
        }
    __syncthreads();

    // ---- phase 2: msg = h1 @ W2 + b2 -> bf16 tile in sX front ----
    f32x4 acc2[4][2];
#pragma unroll
    for (int m = 0; m < 4; ++m)
#pragma unroll
      for (int n = 0; n < 2; ++n)
        acc2[m][n] = (f32x4){bs2[n], bs2[n], bs2[n], bs2[n]};
#pragma unroll
    for (int ks = 0; ks < 4; ++ks) {
      bf16x8 a[4];
#pragma unroll
      for (int m = 0; m < 4; ++m) {
        const int row = m * 16 + l15;
        a[m] = *(const bf16x8*)((const char*)sH + row * 256 + (((4 * ks + lq) ^ (row & 7)) * 16));
      }
#pragma unroll
      for (int m = 0; m < 4; ++m)
#pragma unroll
        for (int n = 0; n < 2; ++n)
          acc2[m][n] = mfma16(a[m], b2f[ks][n], acc2[m][n]);
    }
#pragma unroll
    for (int m = 0; m < 4; ++m)
#pragma unroll
      for (int n = 0; n < 2; ++n)
#pragma unroll
        for (int i = 0; i < 4; ++i) {
          const int row = m * 16 + lq * 4 + i;
          const int col = wv * 32 + n * 16 + l15;
          *(unsigned short*)((char*)sX + row * 256 +
                             ((((col >> 3) ^ (row & 7)) * 16) + (col & 7) * 2)) = f2bf(acc2[m][n][i]);
        }
    __syncthreads();

    // ---- out-store: fp8 row appended to dst-bucket stream ----
    {
      const int d = sDst[r];
      int gpos = -1;
      if (p == 0) {
        const int b = d >> 6;
        const int slot = atomicAdd(&bcur[b], 1);
        gpos = (slot < BCAP) ? b * BCAP + slot : -1;   // overflow: drop (P ~ e^-100)
        if (gpos >= 0) dst8[gpos] = (unsigned char)(d & 63);
      }
      gpos = __shfl(gpos, lane & 60);  // broadcast from the row's p==0 lane
      if (gpos >= 0) {
        unsigned int ww[8];
#pragma unroll
        for (int j = 0; j < 4; ++j) {
          const int cc = 4 * p + j;
          const u32x4 ch = *(const u32x4*)((const char*)sX + r * 256 + ((cc ^ rs) * 16));
          float f[8];
#pragma unroll
          for (int q = 0; q < 4; ++q) {
            f[2 * q]     = __builtin_bit_cast(float, ch[q] << 16);
            f[2 * q + 1] = __builtin_bit_cast(float, ch[q] & 0xffff0000u);
          }
          unsigned int w0 = __builtin_amdgcn_cvt_pk_fp8_f32(f[0], f[1], 0, false);
          w0 = __builtin_amdgcn_cvt_pk_fp8_f32(f[2], f[3], w0, true);
          unsigned int w1 = __builtin_amdgcn_cvt_pk_fp8_f32(f[4], f[5], 0, false);
          w1 = __builtin_amdgcn_cvt_pk_fp8_f32(f[6], f[7], w1, true);
          ww[2 * j] = w0; ww[2 * j + 1] = w1;
        }
        unsigned int* mrow = msgs + (size_t)gpos * 32 + 8 * p;
        *(u32x4*)(mrow)     = (u32x4){ww[0], ww[1], ww[2], ww[3]};
        *(u32x4*)(mrow + 4) = (u32x4){ww[4], ww[5], ww[6], ww[7]};
      }
    }
  }
}

// ---------------------------------------------------------------------------
// aggregate: one block per bucket; sequential fp8 msg read -> LDS f32
// accumulate (ds atomics, bank-parallel) -> agg slice + degree writeback.
// ---------------------------------------------------------------------------
__global__ __launch_bounds__(256) void agg_kernel(
    const unsigned int* __restrict__ msgs,
    const unsigned char* __restrict__ dst8,
    const int* __restrict__ bcur,
    float* __restrict__ agg,
    int* __restrict__ deg)
{
  __shared__ float sAgg[64 * 128];  // 32 KB
  __shared__ int sDeg[64];

  const int b = blockIdx.x;
  const int t = threadIdx.x;

  // zero LDS
#pragma unroll
  for (int k = 0; k < 8; ++k)
    *(f32x4*)(sAgg + (k * 256 + t) * 4) = (f32x4){0.f, 0.f, 0.f, 0.f};
  if (t < 64) sDeg[t] = 0;
  __syncthreads();

  const int n = min(bcur[b], BCAP);
  const size_t base = (size_t)b * BCAP;

  for (int i0 = 0; i0 < n; i0 += 8) {
    const int row = i0 + (t >> 5);
    const int dw = t & 31;
    if (row < n) {
      const unsigned int m = msgs[(base + row) * 32 + dw];
      const int d = dst8[base + row];
      const f32x2 lo = __builtin_amdgcn_cvt_pk_f32_fp8((int)m, false);
      const f32x2 hi = __builtin_amdgcn_cvt_pk_f32_fp8((int)m, true);
      float* rowp = sAgg + d * 128 + dw * 4;
      atomicAdd(rowp + 0, lo[0]);
      atomicAdd(rowp + 1, lo[1]);
      atomicAdd(rowp + 2, hi[0]);
      atomicAdd(rowp + 3, hi[1]);
      if (dw == 0) atomicAdd(&sDeg[d], 1);
    }
  }
  __syncthreads();

  // writeback: 64 rows x 128 f32
  const int r = t >> 2;
  const int p = t & 3;
  const int node = b * 64 + r;
  if (node < NN) {
#pragma unroll
    for (int k = 0; k < 8; ++k)
      *(f32x4*)(agg + (size_t)node * 128 + p * 32 + k * 4) =
          *(const f32x4*)(sAgg + r * 128 + p * 32 + k * 4);
  }
  if (t < 64 && b * 64 + t < NN) deg[b * 64 + t] = sDeg[t];
}

// ---------------------------------------------------------------------------
// update MLP phase 1 in full f32 (VALU): h1 = relu(X @ U1 + b1), K = 320
// ---------------------------------------------------------------------------
__global__ __launch_bounds__(128, 3) void upd1_kernel(
    const float* __restrict__ node_state,
    const float* __restrict__ agg,
    const int* __restrict__ cnt,
    const float* __restrict__ u1,    // [320][128] f32
    const float* __restrict__ b1,
    const float* __restrict__ gs,    // [64] f32
    float* __restrict__ h1out)
{
  const int n = blockIdx.x * 128 + threadIdx.x;
  const bool act = n < NN;
  const size_t row = (size_t)(act ? n : 0) * 128;

  f32x4 acc[32];
#pragma unroll
  for (int c = 0; c < 32; ++c) acc[c] = *(const f32x4*)(b1 + 4 * c);

  const float rdeg = act ? (1.0f / (float)max(cnt[n], 1)) : 0.0f;

  for (int k4 = 0; k4 < 32; ++k4) {
    const f32x4 x = *(const f32x4*)(node_state + row + 4 * k4);
#pragma unroll
    for (int kk = 0; kk < 4; ++kk) {
      const float xk = x[kk];
      const float* wr = u1 + (size_t)(4 * k4 + kk) * 128;
#pragma unroll
      for (int c = 0; c < 32; ++c) acc[c] += xk * *(const f32x4*)(wr + 4 * c);
    }
  }
  for (int k4 = 0; k4 < 32; ++k4) {
    const f32x4 x = *(const f32x4*)(agg + row + 4 * k4);
#pragma unroll
    for (int kk = 0; kk < 4; ++kk) {
      const float xk = x[kk] * rdeg;
      const float* wr = u1 + (size_t)(128 + 4 * k4 + kk) * 128;
#pragma unroll
      for (int c = 0; c < 32; ++c) acc[c] += xk * *(const f32x4*)(wr + 4 * c);
    }
  }
  for (int k = 0; k < 64; ++k) {
    const float xk = gs[k];
    const float* wr = u1 + (size_t)(256 + k) * 128;
#pragma unroll
    for (int c = 0; c < 32; ++c) acc[c] += xk * *(const f32x4*)(wr + 4 * c);
  }

  if (act) {
    float* o = h1out + (size_t)n * 128;
#pragma unroll
    for (int c = 0; c < 32; ++c) {
      f32x4 v = acc[c];
#pragma unroll
      for (int i = 0; i < 4; ++i) v[i] = v[i] > 0.f ? v[i] : 0.f;
      *(f32x4*)(o + 4 * c) = v;
    }
  }
}

// ---------------------------------------------------------------------------
// update MLP phase 2 + residual + LayerNorm, full f32 (VALU)
// ---------------------------------------------------------------------------
__global__ __launch_bounds__(128, 3) void upd2_kernel(
    const float* __restrict__ node_state,
    const float* __restrict__ h1,
    const float* __restrict__ u2,    // [128][128] f32
    const float* __restrict__ b2,
    const float* __restrict__ lng,
    const float* __restrict__ lnb,
    float* __restrict__ out)
{
  const int n = blockIdx.x * 128 + threadIdx.x;
  const bool act = n < NN;
  const size_t row = (size_t)(act ? n : 0) * 128;

  f32x4 acc[32];
#pragma unroll
  for (int c = 0; c < 32; ++c) acc[c] = *(const f32x4*)(b2 + 4 * c);

  for (int k4 = 0; k4 < 32; ++k4) {
    const f32x4 h = *(const f32x4*)(h1 + row + 4 * k4);
#pragma unroll
    for (int kk = 0; kk < 4; ++kk) {
      const float hk = h[kk];
      const float* wr = u2 + (size_t)(4 * k4 + kk) * 128;
#pragma unroll
      for (int c = 0; c < 32; ++c) acc[c] += hk * *(const f32x4*)(wr + 4 * c);
    }
  }

  if (act) {
    float s = 0.f, s2 = 0.f;
#pragma unroll
    for (int c = 0; c < 32; ++c) {
      const f32x4 nd = *(const f32x4*)(node_state + row + 4 * c);
      f32x4 x = nd + acc[c];
      acc[c] = x;
#pragma unroll
      for (int i = 0; i < 4; ++i) { s += x[i]; s2 += x[i] * x[i]; }
    }
    const float mu = s * (1.0f / 128.0f);
    float var = s2 * (1.0f / 128.0f) - mu * mu;
    var = var < 0.f ? 0.f : var;
    const float rstd = rsqrtf(var + 1e-5f);
    float* o = out + (size_t)n * 128;
#pragma unroll
    for (int c = 0; c < 32; ++c) {
      const f32x4 g = *(const f32x4*)(lng + 4 * c);
      const f32x4 b = *(const f32x4*)(lnb + 4 * c);
      f32x4 x = acc[c];
#pragma unroll
      for (int i = 0; i < 4; ++i) x[i] = (x[i] - mu) * rstd * g[i] + b[i];
      *(f32x4*)(o + 4 * c) = x;
    }
  }
}

// ---------------------------------------------------------------------------
extern "C" void kernel_launch(void* const* d_in, const int* in_sizes, int n_in,
                              void* d_out, int out_size, void* d_ws, size_t ws_size,
                              hipStream_t stream)
{
  const float* node_state = (const float*)d_in[0];
  const int* ei           = (const int*)d_in[1];   // int64 in reference -> int32 from harness
  const float* edge_state = (const float*)d_in[2];
  const float* gstate     = (const float*)d_in[3];
  const float* msg_w1     = (const float*)d_in[4];
  const float* msg_b1     = (const float*)d_in[5];
  const float* msg_w2     = (const float*)d_in[6];
  const float* msg_b2     = (const float*)d_in[7];
  const float* upd_w1     = (const float*)d_in[8];
  const float* upd_b1     = (const float*)d_in[9];
  const float* upd_w2     = (const float*)d_in[10];
  const float* upd_b2     = (const float*)d_in[11];
  const float* ln_g       = (const float*)d_in[12];
  const float* ln_b       = (const float*)d_in[13];

  char* ws = (char*)d_ws;
  // agg region double-books node_bf: node_bf read only by edge_msg_kernel;
  // agg first written by agg_kernel AFTER edge_msg completes (stream order).
  float* agg              = (float*)(ws + 0);                  //  51,200,000
  unsigned short* node_bf = (unsigned short*)(ws + 0);         //  25,600,000 (alias)
  int* deg                = (int*)(ws + 51200000);             //     400,000
  int* bcur               = (int*)(ws + 51600000);             //       6,252 (pad 8192)
  unsigned short* w1b     = (unsigned short*)(ws + 51608192);  //      65,536
  unsigned short* w2b     = (unsigned short*)(ws + 51673728);  //      32,768
  unsigned short* gb      = (unsigned short*)(ws + 51706496);  //         128 (pad 256)
  unsigned char* dst8     = (unsigned char*)(ws + 51706752);   //   2,400,768 (pad to 54108160)
  unsigned int* msgs      = (unsigned int*)(ws + 54108160);    // 307,298,304 (fp8 [NBK*BCAP][128])
  float* h1buf            = (float*)(ws + 54108160);           // aliases msgs (dead by upd1)
  (void)ws_size; (void)in_sizes; (void)n_in; (void)out_size;

  hipMemsetAsync(bcur, 0, 8192, stream);
  hipLaunchKernelGGL(convert_kernel, dim3(2048), dim3(256), 0, stream,
                     node_state, msg_w1, msg_w2, gstate, node_bf, w1b, w2b, gb);
  hipLaunchKernelGGL(edge_msg_kernel, dim3(768), dim3(256), 0, stream,
                     ei, edge_state, node_bf, w1b, w2b, msg_b1, msg_b2, gb,
                     bcur, msgs, dst8);
  hipLaunchKernelGGL(agg_kernel, dim3(NBK), dim3(256), 0, stream,
                     msgs, dst8, bcur, agg, deg);
  hipLaunchKernelGGL(upd1_kernel, dim3((NN + 127) / 128), dim3(128), 0, stream,
                     node_state, agg, deg, upd_w1, upd_b1, gstate, h1buf);
  hipLaunchKernelGGL(upd2_kernel, dim3((NN + 127) / 128), dim3(128), 0, stream,
                     node_state, h1buf, upd_w2, upd_b2, ln_g, ln_b, (float*)d_out);
}

// Round 9
// 1369.432 us; speedup vs baseline: 1.8143x; 1.8143x over previous
//
#include <hip/hip_runtime.h>
#include <hip/hip_bf16.h>
#include <stdint.h>

#define NN 100000
#define NE 1600000

typedef __attribute__((ext_vector_type(4))) float f32x4;
typedef __attribute__((ext_vector_type(8))) __bf16 bf16x8;
typedef __attribute__((ext_vector_type(8))) short s16x8;
typedef __attribute__((ext_vector_type(4))) unsigned int u32x4;

__device__ __forceinline__ unsigned short f2bf(float f) {
  unsigned int u = __builtin_bit_cast(unsigned int, f);
  u += 0x7fffu + ((u >> 16) & 1u);
  return (unsigned short)(u >> 16);
}

__device__ __forceinline__ f32x4 mfma16(bf16x8 a, bf16x8 b, f32x4 c) {
  return __builtin_amdgcn_mfma_f32_16x16x32_bf16(a, b, c, 0, 0, 0);
}

// ---------------------------------------------------------------------------
// setup: node_state -> bf16 table; msg weights + global -> bf16
// ---------------------------------------------------------------------------
__global__ void convert_kernel(const float* __restrict__ ns,
                               const float* __restrict__ w1, const float* __restrict__ w2,
                               const float* __restrict__ g,
                               unsigned short* __restrict__ node_bf,
                               unsigned short* __restrict__ w1b, unsigned short* __restrict__ w2b,
                               unsigned short* __restrict__ gb)
{
  const int tid = blockIdx.x * 256 + threadIdx.x;
  const int stride = gridDim.x * 256;
  for (int i = tid; i < NN * 128; i += stride) node_bf[i] = f2bf(ns[i]);
  if (tid < 256 * 128) w1b[tid] = f2bf(w1[tid]);
  if (tid < 128 * 128) w2b[tid] = f2bf(w2[tid]);
  if (tid < 64) gb[tid] = f2bf(g[tid]);
}

// ---------------------------------------------------------------------------
// edge kernel (r3 structure + proven levers):
// msg = MLP(concat(node_bf[src], edge_state, gs)) via bf16 MFMA;
// scatter: direct f32 atomicAdd into agg[dst] from accumulator registers.
// - register-prefetch double buffer (tile t+grid gathered during tile t)
// - h1 tile aliases staging tile front (LDS 32.3 KB -> 4 blocks/CU)
// ---------------------------------------------------------------------------
__global__ __launch_bounds__(256, 4) void edge_kernel(
    const int* __restrict__ ei,
    const float* __restrict__ edge_state,
    const unsigned short* __restrict__ node_bf,
    const unsigned short* __restrict__ w1b,
    const unsigned short* __restrict__ w2b,
    const float* __restrict__ bias1g,
    const float* __restrict__ bias2g,
    const unsigned short* __restrict__ gb,
    float* __restrict__ agg,
    float* __restrict__ deg)
{
  __shared__ unsigned short sX[64 * 256];  // 32 KB staging; front 16 KB reused as h1 tile
  __shared__ int sDst[64];
  unsigned short* sH = sX;                 // h1 [64][128] swizzled, aliases sX bytes 0..16K

  const int t = threadIdx.x;
  const int lane = t & 63;
  const int wv = t >> 6;
  const int l15 = lane & 15;
  const int lq = lane >> 4;

  // preload W1/W2 B-fragments (per-wave column slice)
  bf16x8 b1f[8][2], b2f[4][2];
  float bs1[2], bs2[2];
  for (int n = 0; n < 2; ++n) {
    const int col = wv * 32 + n * 16 + l15;
    bs1[n] = bias1g[col];
    bs2[n] = bias2g[col];
    for (int ks = 0; ks < 8; ++ks) {
      const int k0 = ks * 32 + lq * 8;
      s16x8 v;
#pragma unroll
      for (int j = 0; j < 8; ++j) v[j] = (short)w1b[(k0 + j) * 128 + col];
      b1f[ks][n] = __builtin_bit_cast(bf16x8, v);
    }
    for (int ks = 0; ks < 4; ++ks) {
      const int k0 = ks * 32 + lq * 8;
      s16x8 v;
#pragma unroll
      for (int j = 0; j < 8; ++j) v[j] = (short)w2b[(k0 + j) * 128 + col];
      b2f[ks][n] = __builtin_bit_cast(bf16x8, v);
    }
  }

  const int r = t >> 2;   // edge row within tile
  const int p = t & 3;    // quarter of the row
  const int rs = r & 7;   // swizzle key

  u32x4 gR0, gR1;
  {
    const u32x4* g = (const u32x4*)(gb + p * 16);
    gR0 = g[0]; gR1 = g[1];
  }

  const int grid = gridDim.x;
  const int NT = NE / 64;

  // ---- prologue: gather tile0; indices for tile1 ----
  u32x4 pfN[4];
  f32x4 pfE[4];
  int srcNext, dstNext, dstCur;
  {
    const int e0 = blockIdx.x * 64 + r;
    const int s0 = ei[e0];
    dstCur = ei[NE + e0];
    const u32x4* nb = (const u32x4*)(node_bf + (size_t)s0 * 128);
    const f32x4* es = (const f32x4*)(edge_state + (size_t)e0 * 64);
#pragma unroll
    for (int j = 0; j < 4; ++j) { pfN[j] = nb[p * 4 + j]; pfE[j] = es[p * 4 + j]; }
    const int e1 = min((blockIdx.x + grid) * 64 + r, NE - 1);
    srcNext = ei[e1];
    dstNext = ei[NE + e1];
  }

  for (int tile = blockIdx.x; tile < NT; tile += grid) {
    __syncthreads();  // prior iteration's phase-2 reads of sH (sX front) done

    // ---- stage: pure reg -> LDS ----
    if (p == 0) {
      sDst[r] = dstCur;
      atomicAdd(&deg[dstCur], 1.0f);
    }
#pragma unroll
    for (int j = 0; j < 4; ++j) {   // node chunks 0..15 (bf16)
      const int c = p * 4 + j;
      *(u32x4*)((char*)sX + r * 512 + ((c ^ rs) * 16)) = pfN[j];
    }
    {  // edge chunks 16..23 (f32 -> bf16)
      unsigned short bufa[8], bufb[8];
#pragma unroll
      for (int i = 0; i < 4; ++i) {
        bufa[i] = f2bf(pfE[0][i]); bufa[4 + i] = f2bf(pfE[1][i]);
        bufb[i] = f2bf(pfE[2][i]); bufb[4 + i] = f2bf(pfE[3][i]);
      }
      const int c = 16 + 2 * p;
      *(u32x4*)((char*)sX + r * 512 + ((c ^ rs) * 16)) = *(u32x4*)bufa;
      *(u32x4*)((char*)sX + r * 512 + (((c + 1) ^ rs) * 16)) = *(u32x4*)bufb;
    }
    {  // global chunks 24..31
      const int c = 24 + 2 * p;
      *(u32x4*)((char*)sX + r * 512 + ((c ^ rs) * 16)) = gR0;
      *(u32x4*)((char*)sX + r * 512 + (((c + 1) ^ rs) * 16)) = gR1;
    }
    __syncthreads();

    // ---- issue next tile's gathers (latency hidden under MFMA phases) ----
    {
      const int tn = tile + grid;
      const int eN = min(tn * 64 + r, NE - 1);
      const u32x4* nb = (const u32x4*)(node_bf + (size_t)srcNext * 128);
      const f32x4* es = (const f32x4*)(edge_state + (size_t)eN * 64);
#pragma unroll
      for (int j = 0; j < 4; ++j) { pfN[j] = nb[p * 4 + j]; pfE[j] = es[p * 4 + j]; }
      dstCur = dstNext;
      const int e2 = min((tn + grid) * 64 + r, NE - 1);
      srcNext = ei[e2];
      dstNext = ei[NE + e2];
    }

    // ---- phase 1: h1 = relu(X @ W1 + b1) ----
    f32x4 acc[4][2];
#pragma unroll
    for (int m = 0; m < 4; ++m)
#pragma unroll
      for (int n = 0; n < 2; ++n)
        acc[m][n] = (f32x4){bs1[n], bs1[n], bs1[n], bs1[n]};
#pragma unroll
    for (int ks = 0; ks < 8; ++ks) {
      bf16x8 a[4];
#pragma unroll
      for (int m = 0; m < 4; ++m) {
        const int row = m * 16 + l15;
        a[m] = *(const bf16x8*)((const char*)sX + row * 512 + (((4 * ks + lq) ^ (row & 7)) * 16));
      }
#pragma unroll
      for (int m = 0; m < 4; ++m)
#pragma unroll
        for (int n = 0; n < 2; ++n)
          acc[m][n] = mfma16(a[m], b1f[ks][n], acc[m][n]);
    }
    __syncthreads();  // all phase-1 sX reads done before overwriting sX front with h1

    // relu + store h1 (swizzled bf16 [64][128]) into sX front
#pragma unroll
    for (int m = 0; m < 4; ++m)
#pragma unroll
      for (int n = 0; n < 2; ++n)
#pragma unroll
        for (int i = 0; i < 4; ++i) {
          const int row = m * 16 + lq * 4 + i;
          const int col = wv * 32 + n * 16 + l15;
          float v = acc[m][n][i];
          v = v > 0.f ? v : 0.f;
          *(unsigned short*)((char*)sH + row * 256 +
                             ((((col >> 3) ^ (row & 7)) * 16) + (col & 7) * 2)) = f2bf(v);
        }
    __syncthreads();

    // ---- phase 2: msg = h1 @ W2 + b2; scatter straight from registers ----
    f32x4 acc2[4][2];
#pragma unroll
    for (int m = 0; m < 4; ++m)
#pragma unroll
      for (int n = 0; n < 2; ++n)
        acc2[m][n] = (f32x4){bs2[n], bs2[n], bs2[n], bs2[n]};
#pragma unroll
    for (int ks = 0; ks < 4; ++ks) {
      bf16x8 a[4];
#pragma unroll
      for (int m = 0; m < 4; ++m) {
        const int row = m * 16 + l15;
        a[m] = *(const bf16x8*)((const char*)sH + row * 256 + (((4 * ks + lq) ^ (row & 7)) * 16));
      }
#pragma unroll
      for (int m = 0; m < 4; ++m)
#pragma unroll
        for (int n = 0; n < 2; ++n)
          acc2[m][n] = mfma16(a[m], b2f[ks][n], acc2[m][n]);
    }
#pragma unroll
    for (int m = 0; m < 4; ++m)
#pragma unroll
      for (int i = 0; i < 4; ++i) {
        const int row = m * 16 + lq * 4 + i;
        const int d = sDst[row];
#pragma unroll
        for (int n = 0; n < 2; ++n) {
          const int col = wv * 32 + n * 16 + l15;
          atomicAdd(&agg[(size_t)d * 128 + col], acc2[m][n][i]);
        }
      }
  }
}

// ---------------------------------------------------------------------------
// update MLP phase 1 in full f32 (VALU): h1 = relu(X @ U1 + b1), K = 320
// ---------------------------------------------------------------------------
__global__ __launch_bounds__(128, 3) void upd1_kernel(
    const float* __restrict__ node_state,
    const float* __restrict__ agg,
    const float* __restrict__ deg,
    const float* __restrict__ u1,    // [320][128] f32
    const float* __restrict__ b1,
    const float* __restrict__ gs,    // [64] f32
    float* __restrict__ h1out)
{
  const int n = blockIdx.x * 128 + threadIdx.x;
  const bool act = n < NN;
  const size_t row = (size_t)(act ? n : 0) * 128;

  f32x4 acc[32];
#pragma unroll
  for (int c = 0; c < 32; ++c) acc[c] = *(const f32x4*)(b1 + 4 * c);

  const float rdeg = act ? (1.0f / fmaxf(deg[n], 1.0f)) : 0.0f;

  for (int k4 = 0; k4 < 32; ++k4) {
    const f32x4 x = *(const f32x4*)(node_state + row + 4 * k4);
#pragma unroll
    for (int kk = 0; kk < 4; ++kk) {
      const float xk = x[kk];
      const float* wr = u1 + (size_t)(4 * k4 + kk) * 128;
#pragma unroll
      for (int c = 0; c < 32; ++c) acc[c] += xk * *(const f32x4*)(wr + 4 * c);
    }
  }
  for (int k4 = 0; k4 < 32; ++k4) {
    const f32x4 x = *(const f32x4*)(agg + row + 4 * k4);
#pragma unroll
    for (int kk = 0; kk < 4; ++kk) {
      const float xk = x[kk] * rdeg;
      const float* wr = u1 + (size_t)(128 + 4 * k4 + kk) * 128;
#pragma unroll
      for (int c = 0; c < 32; ++c) acc[c] += xk * *(const f32x4*)(wr + 4 * c);
    }
  }
  for (int k = 0; k < 64; ++k) {
    const float xk = gs[k];
    const float* wr = u1 + (size_t)(256 + k) * 128;
#pragma unroll
    for (int c = 0; c < 32; ++c) acc[c] += xk * *(const f32x4*)(wr + 4 * c);
  }

  if (act) {
    float* o = h1out + (size_t)n * 128;
#pragma unroll
    for (int c = 0; c < 32; ++c) {
      f32x4 v = acc[c];
#pragma unroll
      for (int i = 0; i < 4; ++i) v[i] = v[i] > 0.f ? v[i] : 0.f;
      *(f32x4*)(o + 4 * c) = v;
    }
  }
}

// ---------------------------------------------------------------------------
// update MLP phase 2 + residual + LayerNorm, full f32 (VALU)
// ---------------------------------------------------------------------------
__global__ __launch_bounds__(128, 3) void upd2_kernel(
    const float* __restrict__ node_state,
    const float* __restrict__ h1,
    const float* __restrict__ u2,    // [128][128] f32
    const float* __restrict__ b2,
    const float* __restrict__ lng,
    const float* __restrict__ lnb,
    float* __restrict__ out)
{
  const int n = blockIdx.x * 128 + threadIdx.x;
  const bool act = n < NN;
  const size_t row = (size_t)(act ? n : 0) * 128;

  f32x4 acc[32];
#pragma unroll
  for (int c = 0; c < 32; ++c) acc[c] = *(const f32x4*)(b2 + 4 * c);

  for (int k4 = 0; k4 < 32; ++k4) {
    const f32x4 h = *(const f32x4*)(h1 + row + 4 * k4);
#pragma unroll
    for (int kk = 0; kk < 4; ++kk) {
      const float hk = h[kk];
      const float* wr = u2 + (size_t)(4 * k4 + kk) * 128;
#pragma unroll
      for (int c = 0; c < 32; ++c) acc[c] += hk * *(const f32x4*)(wr + 4 * c);
    }
  }

  if (act) {
    float s = 0.f, s2 = 0.f;
#pragma unroll
    for (int c = 0; c < 32; ++c) {
      const f32x4 nd = *(const f32x4*)(node_state + row + 4 * c);
      f32x4 x = nd + acc[c];
      acc[c] = x;
#pragma unroll
      for (int i = 0; i < 4; ++i) { s += x[i]; s2 += x[i] * x[i]; }
    }
    const float mu = s * (1.0f / 128.0f);
    float var = s2 * (1.0f / 128.0f) - mu * mu;
    var = var < 0.f ? 0.f : var;
    const float rstd = rsqrtf(var + 1e-5f);
    float* o = out + (size_t)n * 128;
#pragma unroll
    for (int c = 0; c < 32; ++c) {
      const f32x4 g = *(const f32x4*)(lng + 4 * c);
      const f32x4 b = *(const f32x4*)(lnb + 4 * c);
      f32x4 x = acc[c];
#pragma unroll
      for (int i = 0; i < 4; ++i) x[i] = (x[i] - mu) * rstd * g[i] + b[i];
      *(f32x4*)(o + 4 * c) = x;
    }
  }
}

// ---------------------------------------------------------------------------
extern "C" void kernel_launch(void* const* d_in, const int* in_sizes, int n_in,
                              void* d_out, int out_size, void* d_ws, size_t ws_size,
                              hipStream_t stream)
{
  const float* node_state = (const float*)d_in[0];
  const int* ei           = (const int*)d_in[1];   // int64 in reference -> int32 from harness
  const float* edge_state = (const float*)d_in[2];
  const float* gstate     = (const float*)d_in[3];
  const float* msg_w1     = (const float*)d_in[4];
  const float* msg_b1     = (const float*)d_in[5];
  const float* msg_w2     = (const float*)d_in[6];
  const float* msg_b2     = (const float*)d_in[7];
  const float* upd_w1     = (const float*)d_in[8];
  const float* upd_b1     = (const float*)d_in[9];
  const float* upd_w2     = (const float*)d_in[10];
  const float* upd_b2     = (const float*)d_in[11];
  const float* ln_g       = (const float*)d_in[12];
  const float* ln_b       = (const float*)d_in[13];

  char* ws = (char*)d_ws;
  float* agg              = (float*)(ws + 0);                  //  51,200,000
  float* deg              = (float*)(ws + 51200000);           //     400,000
  unsigned short* node_bf = (unsigned short*)(ws + 51600000);  //  25,600,000
  unsigned short* w1b     = (unsigned short*)(ws + 77200000);  //      65,536
  unsigned short* w2b     = (unsigned short*)(ws + 77265536);  //      32,768
  unsigned short* gb      = (unsigned short*)(ws + 77298304);  //         128
  float* h1buf            = (float*)(ws + 77300000);           //  51,200,000
  (void)ws_size; (void)in_sizes; (void)n_in; (void)out_size;

  hipMemsetAsync(ws, 0, 51600000, stream);  // agg + deg
  hipLaunchKernelGGL(convert_kernel, dim3(2048), dim3(256), 0, stream,
                     node_state, msg_w1, msg_w2, gstate, node_bf, w1b, w2b, gb);
  hipLaunchKernelGGL(edge_kernel, dim3(1024), dim3(256), 0, stream,
                     ei, edge_state, node_bf, w1b, w2b, msg_b1, msg_b2, gb, agg, deg);
  hipLaunchKernelGGL(upd1_kernel, dim3((NN + 127) / 128), dim3(128), 0, stream,
                     node_state, agg, deg, upd_w1, upd_b1, gstate, h1buf);
  hipLaunchKernelGGL(upd2_kernel, dim3((NN + 127) / 128), dim3(128), 0, stream,
                     node_state, h1buf, upd_w2, upd_b2, ln_g, ln_b, (float*)d_out);
}